// Round 6
// baseline (3944.478 us; speedup 1.0000x reference)
//
#include <hip/hip_runtime.h>

#define NN 50000
#define DD 32

struct __align__(16) EdgeRec {
    float a;
    int src;
    int e;
    int pad;
};

__device__ __forceinline__ float lrelu(float x) { return fmaxf(x, 0.01f * x); }

__device__ __forceinline__ void lds_copy(float* dst, const float* __restrict__ src, int n) {
    for (int i = threadIdx.x; i < n; i += blockDim.x) dst[i] = src[i];
}

template <int K>
__device__ __forceinline__ void mv_acc(float acc[DD], const float* W, const float x[K]) {
#pragma unroll
    for (int k = 0; k < K; ++k) {
        float xv = x[k];
        const float4* wp = reinterpret_cast<const float4*>(W + k * DD);
#pragma unroll
        for (int j4 = 0; j4 < DD / 4; ++j4) {
            float4 w4 = wp[j4];
            acc[4 * j4 + 0] = fmaf(xv, w4.x, acc[4 * j4 + 0]);
            acc[4 * j4 + 1] = fmaf(xv, w4.y, acc[4 * j4 + 1]);
            acc[4 * j4 + 2] = fmaf(xv, w4.z, acc[4 * j4 + 2]);
            acc[4 * j4 + 3] = fmaf(xv, w4.w, acc[4 * j4 + 3]);
        }
    }
}

__device__ __forceinline__ void load_vec32(float dst[DD], const float* __restrict__ g) {
    const float4* gp = reinterpret_cast<const float4*>(g);
#pragma unroll
    for (int j4 = 0; j4 < DD / 4; ++j4) {
        float4 v = gp[j4];
        dst[4 * j4 + 0] = v.x;
        dst[4 * j4 + 1] = v.y;
        dst[4 * j4 + 2] = v.z;
        dst[4 * j4 + 3] = v.w;
    }
}

// ---------------- CSR build ----------------
__global__ __launch_bounds__(256) void k_hist(const int* __restrict__ ei, int* __restrict__ cnt,
                                              int nE) {
    int e = blockIdx.x * 256 + threadIdx.x;
    if (e < nE) atomicAdd(&cnt[ei[e]], 1);
}

__global__ __launch_bounds__(1024) void k_scan(int* __restrict__ cnt_cur, int* __restrict__ off,
                                               int nN) {
    __shared__ int part[1024];
    int t = threadIdx.x;
    const int CH = (nN + 1023) / 1024;
    int beg = t * CH, end = min(beg + CH, nN);
    int sum = 0;
    for (int i = beg; i < end; ++i) sum += cnt_cur[i];
    part[t] = sum;
    __syncthreads();
    for (int ofs = 1; ofs < 1024; ofs <<= 1) {
        int v = (t >= ofs) ? part[t - ofs] : 0;
        __syncthreads();
        part[t] += v;
        __syncthreads();
    }
    int run = (t == 0) ? 0 : part[t - 1];
    for (int i = beg; i < end; ++i) {
        int c = cnt_cur[i];
        off[i] = run;
        cnt_cur[i] = run;
        run += c;
    }
    if (t == 1023) off[nN] = part[1023];
}

__global__ __launch_bounds__(256) void k_fill(const int* __restrict__ ei,
                                              const float* __restrict__ ea, int* __restrict__ cur,
                                              EdgeRec* __restrict__ rec, int nE) {
    int e = blockIdx.x * 256 + threadIdx.x;
    if (e >= nE) return;
    int src = ei[e];
    int pos = atomicAdd(&cur[src], 1);
    int4 r = make_int4(__float_as_int(ea[e]), src, e, 0);
    reinterpret_cast<int4*>(rec)[pos] = r;
}

// ---- prep: affine-in-a folds. pre = [c1,d1,cu,du,ch,dh] (6x32) ----
__global__ __launch_bounds__(192) void k_prep(const float* __restrict__ w_in,
                                              const float* __restrict__ b_in,
                                              const float* __restrict__ tw1,
                                              const float* __restrict__ tb1,
                                              const float* __restrict__ uw1,
                                              const float* __restrict__ ub1,
                                              const float* __restrict__ hw1,
                                              const float* __restrict__ hb1,
                                              float* __restrict__ pre) {
    int t = threadIdx.x;
    int which = t >> 5, f = t & 31;
    if (which >= 6) return;
    const float* W = (which < 2) ? tw1 : (which < 4) ? uw1 : hw1;
    const float* x = (which & 1) ? b_in : w_in;
    const float* badd = (which == 1) ? tb1 : (which == 3) ? ub1 : (which == 5) ? hb1 : nullptr;
    float s = badd ? badd[f] : 0.f;
    for (int k = 0; k < 32; ++k) s = fmaf(x[k], W[k * 32 + f], s);
    pre[which * 32 + f] = s;
}

// ---- prep2: fold adjacent linear maps into 5 32x32 mats + 5 vectors ----
// fold: [0)WA=uw2_0@uw1_1top [1024)WB=uw2_0@tw1_1 [2048)WC=tw2_0@uw1_0bot
//       [3072)WD=tw2_1@uw1_1bot [4096)WE=uw2_1@hw1_bot
//       [5120)vB [5152)vC [5184)vD [5216)addg2 [5248)dh2
__global__ __launch_bounds__(256) void k_prep2(
    const float* __restrict__ tw1, const float* __restrict__ tb1, const float* __restrict__ tw2,
    const float* __restrict__ tb2, const float* __restrict__ uw1, const float* __restrict__ ub1,
    const float* __restrict__ uw2, const float* __restrict__ ub2, const float* __restrict__ hw1,
    const float* __restrict__ pre, float* __restrict__ fold) {
    for (int e = threadIdx.x; e < 5 * 1024 + 5 * 32; e += 256) {
        if (e < 5120) {
            int m = e >> 10, r = e & 1023, i = r >> 5, j = r & 31;
            const float* A;
            const float* B;
            switch (m) {
                case 0: A = uw2;        B = uw1 + 2048; break;
                case 1: A = uw2;        B = tw1 + 1024; break;
                case 2: A = tw2;        B = uw1 + 1024; break;
                case 3: A = tw2 + 1024; B = uw1 + 3072; break;
                default: A = uw2 + 1024; B = hw1 + 1024; break;
            }
            float s = 0.f;
            for (int k = 0; k < 32; ++k) s = fmaf(A[i * 32 + k], B[k * 32 + j], s);
            fold[e] = s;
        } else {
            int r = e - 5120;
            int v = r >> 5, f = r & 31;
            const float* x;
            const float* B;
            float s;
            switch (v) {
                case 0: x = ub2;      B = tw1 + 1024; s = tb1[32 + f]; break;  // vB
                case 1: x = tb2;      B = uw1 + 1024; s = 0.f;         break;  // vC
                case 2: x = tb2 + 32; B = uw1 + 3072; s = 0.f;         break;  // vD
                case 3: x = ub2;      B = uw1 + 2048; s = ub1[32 + f]; break;  // addg2
                default: x = ub2 + 32; B = hw1 + 1024; s = pre[160 + f]; break;  // dh2
            }
            for (int k = 0; k < 32; ++k) s = fmaf(x[k], B[k * 32 + f], s);
            fold[e] = s;
        }
    }
}

// ---- accum0: M0[n][f] = sum_e lrelu(a_e*c1[f]+d1[f])  (thread per (node,f)) ----
__global__ __launch_bounds__(256) void k_accum0(const EdgeRec* __restrict__ rec,
                                                const int* __restrict__ off,
                                                const float* __restrict__ pre,
                                                float* __restrict__ M0) {
    int tid = blockIdx.x * 256 + threadIdx.x;
    int n = tid >> 5, f = tid & 31;
    if (n >= NN) return;
    float c1f = pre[f], d1f = pre[32 + f];
    int b = off[n], e = off[n + 1];
    float s = 0.f;
    for (int j = b; j < e; ++j) s += lrelu(fmaf(rec[j].a, c1f, d1f));
    M0[(size_t)n * DD + f] = s;
}

// ---- gnode: g[n] = addv + deg*dv + M[n]@W  (thread per (node,f)) ----
__global__ __launch_bounds__(256) void k_gnode(const float* __restrict__ M,
                                               const float* __restrict__ W,
                                               const float* __restrict__ dv,
                                               const float* __restrict__ addv,
                                               const int* __restrict__ off, float* __restrict__ g) {
    __shared__ float LW[1088];
    lds_copy(LW, W, 1024);
    lds_copy(LW + 1024, dv, 32);
    lds_copy(LW + 1056, addv, 32);
    __syncthreads();
    int tid = blockIdx.x * 256 + threadIdx.x;
    int n = tid >> 5, f = tid & 31;
    if (n >= NN) return;
    float deg = (float)(off[n + 1] - off[n]);
    const float* srow = M + (size_t)n * DD;
    float acc = fmaf(deg, LW[1024 + f], LW[1056 + f]);
    for (int k = 0; k < 32; ++k) acc = fmaf(srow[k], LW[k * 32 + f], acc);
    g[(size_t)n * DD + f] = acc;
}

// ---- accum1: Z1[n] = sum_e lrelu(m1@WB + vB), m1 = lrelu(a*cu + g1[n]) ----
// wave per node; g1 row is wave-uniform
__global__ __launch_bounds__(256) void k_accum1(const EdgeRec* __restrict__ rec,
                                                const int* __restrict__ off,
                                                const float* __restrict__ pre,
                                                const float* __restrict__ fold,
                                                const float* __restrict__ g1,
                                                float* __restrict__ Z1) {
    __shared__ __align__(16) float lds[1088];
    lds_copy(lds, fold + 1024, 1024);     // WB
    lds_copy(lds + 1024, fold + 5120, 32);  // vB
    lds_copy(lds + 1056, pre + 64, 32);     // cu
    __syncthreads();
    int wid = (blockIdx.x * 256 + threadIdx.x) >> 6;
    int lane = threadIdx.x & 63;
    if (wid >= NN) return;
    int beg = off[wid], end = off[wid + 1];
    float g1n[DD];
    load_vec32(g1n, g1 + (size_t)wid * DD);
    float acc[DD];
#pragma unroll
    for (int f = 0; f < DD; ++f) acc[f] = 0.f;
    for (int j = beg + lane; j < end; j += 64) {
        float a = rec[j].a;
        float m[DD];
#pragma unroll
        for (int f = 0; f < DD; ++f) m[f] = lrelu(fmaf(a, lds[1056 + f], g1n[f]));
        float z[DD];
#pragma unroll
        for (int f = 0; f < DD; ++f) z[f] = lds[1024 + f];
        mv_acc<DD>(z, lds, m);
#pragma unroll
        for (int f = 0; f < DD; ++f) acc[f] += lrelu(z[f]);
    }
#pragma unroll
    for (int mm = 32; mm; mm >>= 1)
#pragma unroll
        for (int f = 0; f < DD; ++f) acc[f] += __shfl_xor(acc[f], mm, 64);
    if (lane == 0) {
        float* zp = Z1 + (size_t)wid * DD;
#pragma unroll
        for (int f = 0; f < DD; ++f) zp[f] = acc[f];
    }
}

// ---- head (3 matvecs): ev[j] = exp(value) in slot order ----
__global__ __launch_bounds__(256) void k_head3(const EdgeRec* __restrict__ rec, int nE,
                                               const float* __restrict__ pre,
                                               const float* __restrict__ fold,
                                               const float* __restrict__ hw2,
                                               const float* __restrict__ hb2,
                                               const float* __restrict__ hw3,
                                               const float* __restrict__ hb3,
                                               const float* __restrict__ g1,
                                               const float* __restrict__ g2,
                                               float* __restrict__ ev) {
    __shared__ __align__(16) float lds[3233];
    float* Lcu = lds;           // 32
    float* LWA = lds + 32;      // 1024
    float* LWE = lds + 1056;    // 1024
    float* Lhw2 = lds + 2080;   // 1024
    float* Lch = lds + 3104;    // 32
    float* Ldh2 = lds + 3136;   // 32
    float* Lhb2 = lds + 3168;   // 32
    float* Lhw3 = lds + 3200;   // 32
    // hb3 broadcast via Lhw3[?]: store separately at end
    __shared__ float Lhb3;
    lds_copy(Lcu, pre + 64, 32);
    lds_copy(LWA, fold, 1024);
    lds_copy(LWE, fold + 4096, 1024);
    lds_copy(Lhw2, hw2, 1024);
    lds_copy(Lch, pre + 128, 32);
    lds_copy(Ldh2, fold + 5248, 32);
    lds_copy(Lhb2, hb2, 32);
    lds_copy(Lhw3, hw3, 32);
    if (threadIdx.x == 0) Lhb3 = hb3[0];
    __syncthreads();
    int j = blockIdx.x * 256 + threadIdx.x;
    if (j >= nE) return;
    EdgeRec r = rec[j];
    float m1[DD];
    {
        float gg[DD];
        load_vec32(gg, g1 + (size_t)r.src * DD);
#pragma unroll
        for (int f = 0; f < DD; ++f) m1[f] = lrelu(fmaf(r.a, Lcu[f], gg[f]));
    }
    float z[DD];
    load_vec32(z, g2 + (size_t)r.src * DD);
    mv_acc<DD>(z, LWA, m1);
#pragma unroll
    for (int f = 0; f < DD; ++f) z[f] = lrelu(z[f]);  // m2
    float v[DD];
#pragma unroll
    for (int f = 0; f < DD; ++f) v[f] = fmaf(r.a, Lch[f], Ldh2[f]);
    mv_acc<DD>(v, LWE, z);
#pragma unroll
    for (int f = 0; f < DD; ++f) v[f] = lrelu(v[f]);
    float w2[DD];
#pragma unroll
    for (int f = 0; f < DD; ++f) w2[f] = Lhb2[f];
    mv_acc<DD>(w2, Lhw2, v);
    float val = Lhb3;
#pragma unroll
    for (int f = 0; f < DD; ++f) val = fmaf(lrelu(w2[f]), Lhw3[f], val);
    ev[j] = __expf(val);  // max-shift dropped: logits O(1), math identical
}

// ---- denom: one wave per node over CONTIGUOUS ev ----
__global__ __launch_bounds__(256) void k_reduce_den(const float* __restrict__ ev,
                                                    const int* __restrict__ off,
                                                    float* __restrict__ denom) {
    int wid = (blockIdx.x * 256 + threadIdx.x) >> 6;
    int lane = threadIdx.x & 63;
    if (wid >= NN) return;
    int beg = off[wid], end = off[wid + 1];
    float acc = 0.f;
    for (int j = beg + lane; j < end; j += 64) acc += ev[j];
#pragma unroll
    for (int m = 32; m; m >>= 1) acc += __shfl_xor(acc, m, 64);
    if (lane == 0) denom[wid] = acc;
}

// ---- normalize: out[rec.e] = ev[j] / denom[rec.src] ----
__global__ __launch_bounds__(256) void k_norm(const EdgeRec* __restrict__ rec,
                                              const float* __restrict__ ev,
                                              const float* __restrict__ denom,
                                              float* __restrict__ out, int nE) {
    int j = blockIdx.x * 256 + threadIdx.x;
    if (j >= nE) return;
    EdgeRec r = rec[j];
    out[r.e] = ev[j] / denom[r.src];
}

extern "C" void kernel_launch(void* const* d_in, const int* in_sizes, int n_in, void* d_out,
                              int out_size, void* d_ws, size_t ws_size, hipStream_t stream) {
    const float* ea = (const float*)d_in[0];
    const int* ei = (const int*)d_in[1];
    const float* w_in = (const float*)d_in[2];
    const float* b_in = (const float*)d_in[3];
    const float* tw1 = (const float*)d_in[4];
    const float* tb1 = (const float*)d_in[5];
    const float* tw2 = (const float*)d_in[6];
    const float* tb2 = (const float*)d_in[7];
    const float* uw1 = (const float*)d_in[8];
    const float* ub1 = (const float*)d_in[9];
    const float* uw2 = (const float*)d_in[10];
    const float* ub2 = (const float*)d_in[11];
    const float* hw1 = (const float*)d_in[12];
    const float* hb1 = (const float*)d_in[13];
    const float* hw2 = (const float*)d_in[14];
    const float* hb2 = (const float*)d_in[15];
    const float* hw3 = (const float*)d_in[16];
    const float* hb3 = (const float*)d_in[17];

    const int nE = in_sizes[0];

    char* w = (char*)d_ws;
    size_t pos = 0;
    auto alloc = [&](size_t bytes) -> void* {
        void* p = w + pos;
        pos = (pos + bytes + 255) & ~(size_t)255;
        return p;
    };
    int* cnt = (int*)alloc((size_t)NN * 4);
    int* offs = (int*)alloc((size_t)(NN + 1) * 4);
    EdgeRec* rec = (EdgeRec*)alloc((size_t)nE * sizeof(EdgeRec));
    float* M0 = (float*)alloc((size_t)NN * DD * 4);  // + Z1 contiguous; reused as ev later
    float* Z1 = (float*)alloc((size_t)NN * DD * 4);
    float* g1 = (float*)alloc((size_t)NN * DD * 4);
    float* g2 = (float*)alloc((size_t)NN * DD * 4);
    float* denom = (float*)alloc((size_t)NN * 4);
    float* pre = (float*)alloc(6 * 32 * 4);
    float* fold = (float*)alloc((5 * 1024 + 5 * 32) * 4);

    float* ev = M0;  // 8 MB; M0+Z1 = 12.8 MB contiguous, both dead after g1/g2

    hipMemsetAsync(cnt, 0, (size_t)NN * 4, stream);

    int gridE = (nE + 255) / 256;
    int gridNF = (NN * DD + 255) / 256;  // thread per (node,feature)
    int gridW = (NN * 64 + 255) / 256;   // wave per node

    k_prep<<<1, 192, 0, stream>>>(w_in, b_in, tw1, tb1, uw1, ub1, hw1, hb1, pre);
    k_prep2<<<1, 256, 0, stream>>>(tw1, tb1, tw2, tb2, uw1, ub1, uw2, ub2, hw1, pre, fold);
    k_hist<<<gridE, 256, 0, stream>>>(ei, cnt, nE);
    k_scan<<<1, 1024, 0, stream>>>(cnt, offs, NN);
    k_fill<<<gridE, 256, 0, stream>>>(ei, ea, cnt, rec, nE);

    // layer 0 (sum-commuted: no per-edge matvec at all)
    k_accum0<<<gridNF, 256, 0, stream>>>(rec, offs, pre, M0);
    // g1 = M0@WC + deg*vC + du
    k_gnode<<<gridNF, 256, 0, stream>>>(M0, fold + 2048, fold + 5152, pre + 96, offs, g1);

    // layer 1 (1 matvec per edge)
    k_accum1<<<gridW, 256, 0, stream>>>(rec, offs, pre, fold, g1, Z1);
    // g2' = Z1@WD + deg*vD + (ub1_1 + vA)
    k_gnode<<<gridNF, 256, 0, stream>>>(Z1, fold + 3072, fold + 5184, fold + 5216, offs, g2);

    // head (3 matvecs per edge) + softmax
    k_head3<<<gridE, 256, 0, stream>>>(rec, nE, pre, fold, hw2, hb2, hw3, hb3, g1, g2, ev);
    k_reduce_den<<<gridW, 256, 0, stream>>>(ev, offs, denom);
    k_norm<<<gridE, 256, 0, stream>>>(rec, ev, denom, (float*)d_out, nE);
}

// Round 7
// 919.367 us; speedup vs baseline: 4.2904x; 4.2904x over previous
//
#include <hip/hip_runtime.h>
#include <hip/hip_fp16.h>

#define NN 50000
#define DD 32

struct __align__(16) EdgeRec {
    float a;
    int src;
    int e;
    int pad;
};

__device__ __forceinline__ float lrelu(float x) { return fmaxf(x, 0.01f * x); }

__device__ __forceinline__ void lds_copy(float* dst, const float* __restrict__ src, int n) {
    for (int i = threadIdx.x; i < n; i += blockDim.x) dst[i] = src[i];
}

template <int K>
__device__ __forceinline__ void mv_acc(float acc[DD], const float* W, const float x[K]) {
#pragma unroll
    for (int k = 0; k < K; ++k) {
        float xv = x[k];
        const float4* wp = reinterpret_cast<const float4*>(W + k * DD);
#pragma unroll
        for (int j4 = 0; j4 < DD / 4; ++j4) {
            float4 w4 = wp[j4];
            acc[4 * j4 + 0] = fmaf(xv, w4.x, acc[4 * j4 + 0]);
            acc[4 * j4 + 1] = fmaf(xv, w4.y, acc[4 * j4 + 1]);
            acc[4 * j4 + 2] = fmaf(xv, w4.z, acc[4 * j4 + 2]);
            acc[4 * j4 + 3] = fmaf(xv, w4.w, acc[4 * j4 + 3]);
        }
    }
}

__device__ __forceinline__ void load_vec32(float dst[DD], const float* __restrict__ g) {
    const float4* gp = reinterpret_cast<const float4*>(g);
#pragma unroll
    for (int j4 = 0; j4 < DD / 4; ++j4) {
        float4 v = gp[j4];
        dst[4 * j4 + 0] = v.x;
        dst[4 * j4 + 1] = v.y;
        dst[4 * j4 + 2] = v.z;
        dst[4 * j4 + 3] = v.w;
    }
}

__device__ __forceinline__ unsigned pack2h(float a, float b) {
    __half ha = __float2half_rn(a), hb = __float2half_rn(b);
    return (unsigned)__half_as_ushort(ha) | ((unsigned)__half_as_ushort(hb) << 16);
}

__device__ __forceinline__ void store_row_fp16(__half* __restrict__ row, const float t[DD]) {
    uint4* d4 = reinterpret_cast<uint4*>(row);
#pragma unroll
    for (int q = 0; q < 4; ++q) {
        d4[q] = make_uint4(pack2h(t[8 * q + 0], t[8 * q + 1]), pack2h(t[8 * q + 2], t[8 * q + 3]),
                           pack2h(t[8 * q + 4], t[8 * q + 5]), pack2h(t[8 * q + 6], t[8 * q + 7]));
    }
}

// ---------------- CSR build ----------------
__global__ __launch_bounds__(256) void k_hist(const int* __restrict__ ei, int* __restrict__ cnt,
                                              int nE) {
    int e = blockIdx.x * 256 + threadIdx.x;
    if (e < nE) atomicAdd(&cnt[ei[e]], 1);
}

__global__ __launch_bounds__(1024) void k_scan(int* __restrict__ cnt_cur, int* __restrict__ off,
                                               int nN) {
    __shared__ int part[1024];
    int t = threadIdx.x;
    const int CH = (nN + 1023) / 1024;
    int beg = t * CH, end = min(beg + CH, nN);
    int sum = 0;
    for (int i = beg; i < end; ++i) sum += cnt_cur[i];
    part[t] = sum;
    __syncthreads();
    for (int ofs = 1; ofs < 1024; ofs <<= 1) {
        int v = (t >= ofs) ? part[t - ofs] : 0;
        __syncthreads();
        part[t] += v;
        __syncthreads();
    }
    int run = (t == 0) ? 0 : part[t - 1];
    for (int i = beg; i < end; ++i) {
        int c = cnt_cur[i];
        off[i] = run;
        cnt_cur[i] = run;
        run += c;
    }
    if (t == 1023) off[nN] = part[1023];
}

__global__ __launch_bounds__(256) void k_fill(const int* __restrict__ ei,
                                              const float* __restrict__ ea, int* __restrict__ cur,
                                              EdgeRec* __restrict__ rec, int nE) {
    int e = blockIdx.x * 256 + threadIdx.x;
    if (e >= nE) return;
    int src = ei[e];
    int pos = atomicAdd(&cur[src], 1);
    int4 r = make_int4(__float_as_int(ea[e]), src, e, 0);
    reinterpret_cast<int4*>(rec)[pos] = r;
}

// ---- prep: affine-in-a folds. pre = [c1,d1,cu,du,ch,dh] (6x32) ----
__global__ __launch_bounds__(192) void k_prep(const float* __restrict__ w_in,
                                              const float* __restrict__ b_in,
                                              const float* __restrict__ tw1,
                                              const float* __restrict__ tb1,
                                              const float* __restrict__ uw1,
                                              const float* __restrict__ ub1,
                                              const float* __restrict__ hw1,
                                              const float* __restrict__ hb1,
                                              float* __restrict__ pre) {
    int t = threadIdx.x;
    int which = t >> 5, f = t & 31;
    if (which >= 6) return;
    const float* W = (which < 2) ? tw1 : (which < 4) ? uw1 : hw1;
    const float* x = (which & 1) ? b_in : w_in;
    const float* badd = (which == 1) ? tb1 : (which == 3) ? ub1 : (which == 5) ? hb1 : nullptr;
    float s = badd ? badd[f] : 0.f;
    for (int k = 0; k < 32; ++k) s = fmaf(x[k], W[k * 32 + f], s);
    pre[which * 32 + f] = s;
}

// ---- prep2: fold adjacent linear maps into 5 32x32 mats + 5 vectors ----
// fold: [0)WA=uw2_0@uw1_1top [1024)WB=uw2_0@tw1_1 [2048)WC=tw2_0@uw1_0bot
//       [3072)WD=tw2_1@uw1_1bot [4096)WE=uw2_1@hw1_bot
//       [5120)vB [5152)vC [5184)vD [5216)addg2 [5248)dh2
__global__ __launch_bounds__(256) void k_prep2(
    const float* __restrict__ tw1, const float* __restrict__ tb1, const float* __restrict__ tw2,
    const float* __restrict__ tb2, const float* __restrict__ uw1, const float* __restrict__ ub1,
    const float* __restrict__ uw2, const float* __restrict__ ub2, const float* __restrict__ hw1,
    const float* __restrict__ pre, float* __restrict__ fold) {
    for (int e = threadIdx.x; e < 5 * 1024 + 5 * 32; e += 256) {
        if (e < 5120) {
            int m = e >> 10, r = e & 1023, i = r >> 5, j = r & 31;
            const float* A;
            const float* B;
            switch (m) {
                case 0: A = uw2;        B = uw1 + 2048; break;
                case 1: A = uw2;        B = tw1 + 1024; break;
                case 2: A = tw2;        B = uw1 + 1024; break;
                case 3: A = tw2 + 1024; B = uw1 + 3072; break;
                default: A = uw2 + 1024; B = hw1 + 1024; break;
            }
            float s = 0.f;
            for (int k = 0; k < 32; ++k) s = fmaf(A[i * 32 + k], B[k * 32 + j], s);
            fold[e] = s;
        } else {
            int r = e - 5120;
            int v = r >> 5, f = r & 31;
            const float* x;
            const float* B;
            float s;
            switch (v) {
                case 0: x = ub2;      B = tw1 + 1024; s = tb1[32 + f]; break;  // vB
                case 1: x = tb2;      B = uw1 + 1024; s = 0.f;         break;  // vC
                case 2: x = tb2 + 32; B = uw1 + 3072; s = 0.f;         break;  // vD
                case 3: x = ub2;      B = uw1 + 2048; s = ub1[32 + f]; break;  // addg2
                default: x = ub2 + 32; B = hw1 + 1024; s = pre[160 + f]; break;  // dh2
            }
            for (int k = 0; k < 32; ++k) s = fmaf(x[k], B[k * 32 + f], s);
            fold[e] = s;
        }
    }
}

// ---- accum0: M0[n][f] = sum_e lrelu(a_e*c1[f]+d1[f])  (thread per (node,f)) ----
__global__ __launch_bounds__(256) void k_accum0(const EdgeRec* __restrict__ rec,
                                                const int* __restrict__ off,
                                                const float* __restrict__ pre,
                                                float* __restrict__ M0) {
    int tid = blockIdx.x * 256 + threadIdx.x;
    int n = tid >> 5, f = tid & 31;
    if (n >= NN) return;
    float c1f = pre[f], d1f = pre[32 + f];
    int b = off[n], e = off[n + 1];
    float s = 0.f;
    for (int j = b; j < e; ++j) s += lrelu(fmaf(rec[j].a, c1f, d1f));
    M0[(size_t)n * DD + f] = s;
}

// ---- gnode: g[n] = addv + deg*dv + M[n]@W  (thread per (node,f)) ----
__global__ __launch_bounds__(256) void k_gnode(const float* __restrict__ M,
                                               const float* __restrict__ W,
                                               const float* __restrict__ dv,
                                               const float* __restrict__ addv,
                                               const int* __restrict__ off, float* __restrict__ g) {
    __shared__ float LW[1088];
    lds_copy(LW, W, 1024);
    lds_copy(LW + 1024, dv, 32);
    lds_copy(LW + 1056, addv, 32);
    __syncthreads();
    int tid = blockIdx.x * 256 + threadIdx.x;
    int n = tid >> 5, f = tid & 31;
    if (n >= NN) return;
    float deg = (float)(off[n + 1] - off[n]);
    const float* srow = M + (size_t)n * DD;
    float acc = fmaf(deg, LW[1024 + f], LW[1056 + f]);
    for (int k = 0; k < 32; ++k) acc = fmaf(srow[k], LW[k * 32 + f], acc);
    g[(size_t)n * DD + f] = acc;
}

// ---- z1 (edge-parallel, straight-line): z = lrelu(m1@WB+vB), m1 = lrelu(a*cu+g1[src]) ----
__global__ __launch_bounds__(256) void k_z1(const EdgeRec* __restrict__ rec, int base, int count,
                                            const float* __restrict__ pre,
                                            const float* __restrict__ fold,
                                            const float* __restrict__ g1,
                                            __half* __restrict__ tbuf) {
    __shared__ __align__(16) float lds[1088];
    lds_copy(lds, fold + 1024, 1024);       // WB
    lds_copy(lds + 1024, fold + 5120, 32);  // vB
    lds_copy(lds + 1056, pre + 64, 32);     // cu
    __syncthreads();
    int j = blockIdx.x * 256 + threadIdx.x;
    if (j >= count) return;
    EdgeRec r = rec[base + j];  // coalesced 16B; consecutive j share src
    float m[DD];
    {
        float gg[DD];
        load_vec32(gg, g1 + (size_t)r.src * DD);  // L1-local
#pragma unroll
        for (int f = 0; f < DD; ++f) m[f] = lrelu(fmaf(r.a, lds[1056 + f], gg[f]));
    }
    float z[DD];
#pragma unroll
    for (int f = 0; f < DD; ++f) z[f] = lds[1024 + f];
    mv_acc<DD>(z, lds, m);
#pragma unroll
    for (int f = 0; f < DD; ++f) z[f] = lrelu(z[f]);
    store_row_fp16(tbuf + (size_t)j * DD, z);
}

// ---- segment-sum of fp16 tbuf rows into s[n][f] ----
__global__ __launch_bounds__(256) void k_gather(const __half* __restrict__ tbuf,
                                                const int* __restrict__ off, float* __restrict__ s,
                                                int base, int end, int zero) {
    int tid = blockIdx.x * 256 + threadIdx.x;
    int n = tid >> 5;
    int f = tid & 31;
    if (n >= NN) return;
    if (zero && base <= off[n] && off[n] < end) {
        // first chunk touching this node initializes (avoids pre-memset)
    }
    int b = max(off[n], base);
    int t_ = min(off[n + 1], end);
    float sum = (zero) ? 0.f : s[(size_t)n * DD + f];
    if (b >= t_) {
        if (zero) s[(size_t)n * DD + f] = sum;
        return;
    }
    for (int j = b; j < t_; ++j) sum += __half2float(tbuf[(size_t)(j - base) * DD + f]);
    s[(size_t)n * DD + f] = sum;
}

// ---- head (3 matvecs): ev[j] = exp(value) in slot order ----
__global__ __launch_bounds__(256) void k_head3(const EdgeRec* __restrict__ rec, int nE,
                                               const float* __restrict__ pre,
                                               const float* __restrict__ fold,
                                               const float* __restrict__ hw2,
                                               const float* __restrict__ hb2,
                                               const float* __restrict__ hw3,
                                               const float* __restrict__ hb3,
                                               const float* __restrict__ g1,
                                               const float* __restrict__ g2,
                                               float* __restrict__ ev) {
    __shared__ __align__(16) float lds[3232];
    float* Lcu = lds;          // 32
    float* LWA = lds + 32;     // 1024
    float* LWE = lds + 1056;   // 1024
    float* Lhw2 = lds + 2080;  // 1024
    float* Lch = lds + 3104;   // 32
    float* Ldh2 = lds + 3136;  // 32
    float* Lhb2 = lds + 3168;  // 32
    float* Lhw3 = lds + 3200;  // 32
    __shared__ float Lhb3;
    lds_copy(Lcu, pre + 64, 32);
    lds_copy(LWA, fold, 1024);
    lds_copy(LWE, fold + 4096, 1024);
    lds_copy(Lhw2, hw2, 1024);
    lds_copy(Lch, pre + 128, 32);
    lds_copy(Ldh2, fold + 5248, 32);
    lds_copy(Lhb2, hb2, 32);
    lds_copy(Lhw3, hw3, 32);
    if (threadIdx.x == 0) Lhb3 = hb3[0];
    __syncthreads();
    int j = blockIdx.x * 256 + threadIdx.x;
    if (j >= nE) return;
    EdgeRec r = rec[j];
    float m1[DD];
    {
        float gg[DD];
        load_vec32(gg, g1 + (size_t)r.src * DD);
#pragma unroll
        for (int f = 0; f < DD; ++f) m1[f] = lrelu(fmaf(r.a, Lcu[f], gg[f]));
    }
    float z[DD];
    load_vec32(z, g2 + (size_t)r.src * DD);
    mv_acc<DD>(z, LWA, m1);
#pragma unroll
    for (int f = 0; f < DD; ++f) z[f] = lrelu(z[f]);  // m2
    float v[DD];
#pragma unroll
    for (int f = 0; f < DD; ++f) v[f] = fmaf(r.a, Lch[f], Ldh2[f]);
    mv_acc<DD>(v, LWE, z);
#pragma unroll
    for (int f = 0; f < DD; ++f) v[f] = lrelu(v[f]);
    float w2[DD];
#pragma unroll
    for (int f = 0; f < DD; ++f) w2[f] = Lhb2[f];
    mv_acc<DD>(w2, Lhw2, v);
    float val = Lhb3;
#pragma unroll
    for (int f = 0; f < DD; ++f) val = fmaf(lrelu(w2[f]), Lhw3[f], val);
    ev[j] = __expf(val);  // max-shift dropped: logits O(1), math identical
}

// ---- denom: one wave per node over CONTIGUOUS ev ----
__global__ __launch_bounds__(256) void k_reduce_den(const float* __restrict__ ev,
                                                    const int* __restrict__ off,
                                                    float* __restrict__ denom) {
    int wid = (blockIdx.x * 256 + threadIdx.x) >> 6;
    int lane = threadIdx.x & 63;
    if (wid >= NN) return;
    int beg = off[wid], end = off[wid + 1];
    float acc = 0.f;
    for (int j = beg + lane; j < end; j += 64) acc += ev[j];
#pragma unroll
    for (int m = 32; m; m >>= 1) acc += __shfl_xor(acc, m, 64);
    if (lane == 0) denom[wid] = acc;
}

// ---- normalize: out[rec.e] = ev[j] / denom[rec.src] ----
__global__ __launch_bounds__(256) void k_norm(const EdgeRec* __restrict__ rec,
                                              const float* __restrict__ ev,
                                              const float* __restrict__ denom,
                                              float* __restrict__ out, int nE) {
    int j = blockIdx.x * 256 + threadIdx.x;
    if (j >= nE) return;
    EdgeRec r = rec[j];
    out[r.e] = ev[j] / denom[r.src];
}

extern "C" void kernel_launch(void* const* d_in, const int* in_sizes, int n_in, void* d_out,
                              int out_size, void* d_ws, size_t ws_size, hipStream_t stream) {
    const float* ea = (const float*)d_in[0];
    const int* ei = (const int*)d_in[1];
    const float* w_in = (const float*)d_in[2];
    const float* b_in = (const float*)d_in[3];
    const float* tw1 = (const float*)d_in[4];
    const float* tb1 = (const float*)d_in[5];
    const float* tw2 = (const float*)d_in[6];
    const float* tb2 = (const float*)d_in[7];
    const float* uw1 = (const float*)d_in[8];
    const float* ub1 = (const float*)d_in[9];
    const float* uw2 = (const float*)d_in[10];
    const float* ub2 = (const float*)d_in[11];
    const float* hw1 = (const float*)d_in[12];
    const float* hb1 = (const float*)d_in[13];
    const float* hw2 = (const float*)d_in[14];
    const float* hb2 = (const float*)d_in[15];
    const float* hw3 = (const float*)d_in[16];
    const float* hb3 = (const float*)d_in[17];

    const int nE = in_sizes[0];

    char* w = (char*)d_ws;
    size_t pos = 0;
    auto alloc = [&](size_t bytes) -> void* {
        void* p = w + pos;
        pos = (pos + bytes + 255) & ~(size_t)255;
        return p;
    };
    int* cnt = (int*)alloc((size_t)NN * 4);
    int* offs = (int*)alloc((size_t)(NN + 1) * 4);
    EdgeRec* rec = (EdgeRec*)alloc((size_t)nE * sizeof(EdgeRec));
    float* M0 = (float*)alloc((size_t)NN * DD * 4);  // M0+Z1 contiguous; ev aliases M0 later
    float* Z1 = (float*)alloc((size_t)NN * DD * 4);
    float* g1 = (float*)alloc((size_t)NN * DD * 4);
    float* g2 = (float*)alloc((size_t)NN * DD * 4);
    float* denom = (float*)alloc((size_t)NN * 4);
    float* pre = (float*)alloc(6 * 32 * 4);
    float* fold = (float*)alloc((5 * 1024 + 5 * 32) * 4);
    size_t remain = ws_size > pos ? ws_size - pos : 0;
    __half* tbuf = (__half*)(w + pos);
    size_t chunk = remain / (DD * 2);
    if (chunk > (size_t)nE) chunk = (size_t)nE;
    if (chunk < 4096) chunk = 4096;
    int nchunks = (int)(((size_t)nE + chunk - 1) / chunk);

    float* ev = M0;  // 8 MB; M0+Z1 = 12.8 MB contiguous, both dead after g1/g2

    hipMemsetAsync(cnt, 0, (size_t)NN * 4, stream);

    int gridE = (nE + 255) / 256;
    int gridNF = (NN * DD + 255) / 256;  // thread per (node,feature)
    int gridW = (NN * 64 + 255) / 256;   // wave per node

    k_prep<<<1, 192, 0, stream>>>(w_in, b_in, tw1, tb1, uw1, ub1, hw1, hb1, pre);
    k_prep2<<<1, 256, 0, stream>>>(tw1, tb1, tw2, tb2, uw1, ub1, uw2, ub2, hw1, pre, fold);
    k_hist<<<gridE, 256, 0, stream>>>(ei, cnt, nE);
    k_scan<<<1, 1024, 0, stream>>>(cnt, offs, NN);
    k_fill<<<gridE, 256, 0, stream>>>(ei, ea, cnt, rec, nE);

    // layer 0 (sum-commuted: no per-edge matvec, no staging)
    k_accum0<<<gridNF, 256, 0, stream>>>(rec, offs, pre, M0);
    // g1 = M0@WC + deg*vC + du
    k_gnode<<<gridNF, 256, 0, stream>>>(M0, fold + 2048, fold + 5152, pre + 96, offs, g1);

    // layer 1: edge-parallel z1 (1 matvec, straight-line) + chunked segment-sum
    for (int c = 0; c < nchunks; ++c) {
        int base = (int)((size_t)c * chunk);
        int count = (int)min((size_t)(nE - base), chunk);
        int g = (count + 255) / 256;
        k_z1<<<g, 256, 0, stream>>>(rec, base, count, pre, fold, g1, tbuf);
        k_gather<<<gridNF, 256, 0, stream>>>(tbuf, offs, Z1, base, base + count, c == 0 ? 1 : 0);
    }
    // g2' = Z1@WD + deg*vD + (ub1_1 + vA)
    k_gnode<<<gridNF, 256, 0, stream>>>(Z1, fold + 3072, fold + 5184, fold + 5216, offs, g2);

    // head (3 matvecs per edge) + softmax
    k_head3<<<gridE, 256, 0, stream>>>(rec, nE, pre, fold, hw2, hb2, hw3, hb3, g1, g2, ev);
    k_reduce_den<<<gridW, 256, 0, stream>>>(ev, offs, denom);
    k_norm<<<gridE, 256, 0, stream>>>(rec, ev, denom, (float*)d_out, nE);
}

// Round 8
// 855.452 us; speedup vs baseline: 4.6110x; 1.0747x over previous
//
#include <hip/hip_runtime.h>

#define NN 50000
#define DD 32
#define BLK 256

struct __align__(8) EdgeRec {
    float a;
    int src;
};

__device__ __forceinline__ float lrelu(float x) { return fmaxf(x, 0.01f * x); }

__device__ __forceinline__ void lds_copy(float* dst, const float* __restrict__ src, int n) {
    for (int i = threadIdx.x; i < n; i += blockDim.x) dst[i] = src[i];
}

__device__ __forceinline__ void load_vec32(float dst[DD], const float* __restrict__ g) {
    const float4* gp = reinterpret_cast<const float4*>(g);
#pragma unroll
    for (int j4 = 0; j4 < DD / 4; ++j4) {
        float4 v = gp[j4];
        dst[4 * j4 + 0] = v.x;
        dst[4 * j4 + 1] = v.y;
        dst[4 * j4 + 2] = v.z;
        dst[4 * j4 + 3] = v.w;
    }
}

// uniform-weight matvec: acc[f] += sum_k x[k]*W[k*32+f]; W is a uniform global
// pointer with unroll-constant indices -> compiler emits s_load + v_fmac(v,s,v)
__device__ __forceinline__ void mv_s(float acc[DD], const float* __restrict__ W,
                                     const float x[DD]) {
#pragma unroll
    for (int k = 0; k < DD; ++k) {
        float xv = x[k];
#pragma unroll
        for (int f = 0; f < DD; ++f) acc[f] = fmaf(xv, W[k * DD + f], acc[f]);
    }
}

// ---------------- CSR build ----------------
__global__ __launch_bounds__(256) void k_hist(const int* __restrict__ ei, int* __restrict__ cnt,
                                              int nE) {
    int e = blockIdx.x * 256 + threadIdx.x;
    if (e < nE) atomicAdd(&cnt[ei[e]], 1);
}

__global__ __launch_bounds__(1024) void k_scan(int* __restrict__ cnt_cur, int* __restrict__ off,
                                               int nN) {
    __shared__ int part[1024];
    int t = threadIdx.x;
    const int CH = (nN + 1023) / 1024;
    int beg = t * CH, end = min(beg + CH, nN);
    int sum = 0;
    for (int i = beg; i < end; ++i) sum += cnt_cur[i];
    part[t] = sum;
    __syncthreads();
    for (int ofs = 1; ofs < 1024; ofs <<= 1) {
        int v = (t >= ofs) ? part[t - ofs] : 0;
        __syncthreads();
        part[t] += v;
        __syncthreads();
    }
    int run = (t == 0) ? 0 : part[t - 1];
    for (int i = beg; i < end; ++i) {
        int c = cnt_cur[i];
        off[i] = run;
        cnt_cur[i] = run;
        run += c;
    }
    if (t == 1023) off[nN] = part[1023];
}

// rec[pos] = {a, src} (random 8B scatter, paid once); inv[e] = pos (coalesced)
__global__ __launch_bounds__(256) void k_fill(const int* __restrict__ ei,
                                              const float* __restrict__ ea, int* __restrict__ cur,
                                              EdgeRec* __restrict__ rec, int* __restrict__ inv,
                                              int nE) {
    int e = blockIdx.x * 256 + threadIdx.x;
    if (e >= nE) return;
    int src = ei[e];
    int pos = atomicAdd(&cur[src], 1);
    reinterpret_cast<int2*>(rec)[pos] = make_int2(__float_as_int(ea[e]), src);
    inv[e] = pos;
}

// nstart[b] = node containing slot min(b*BLK, nE-1)
__global__ __launch_bounds__(256) void k_bstart(const int* __restrict__ offs,
                                                int* __restrict__ nstart, int nB, int nE) {
    int b = blockIdx.x * 256 + threadIdx.x;
    if (b > nB) return;
    int s = min(b * BLK, nE - 1);
    int lo = 0, hi = NN - 1;
    while (lo < hi) {
        int mid = (lo + hi + 1) >> 1;
        if (offs[mid] <= s) lo = mid;
        else hi = mid - 1;
    }
    nstart[b] = lo;
}

// ---- prep: affine-in-a folds. pre = [c1,d1,cu,du,ch,dh] (6x32) ----
__global__ __launch_bounds__(192) void k_prep(const float* __restrict__ w_in,
                                              const float* __restrict__ b_in,
                                              const float* __restrict__ tw1,
                                              const float* __restrict__ tb1,
                                              const float* __restrict__ uw1,
                                              const float* __restrict__ ub1,
                                              const float* __restrict__ hw1,
                                              const float* __restrict__ hb1,
                                              float* __restrict__ pre) {
    int t = threadIdx.x;
    int which = t >> 5, f = t & 31;
    if (which >= 6) return;
    const float* W = (which < 2) ? tw1 : (which < 4) ? uw1 : hw1;
    const float* x = (which & 1) ? b_in : w_in;
    const float* badd = (which == 1) ? tb1 : (which == 3) ? ub1 : (which == 5) ? hb1 : nullptr;
    float s = badd ? badd[f] : 0.f;
    for (int k = 0; k < 32; ++k) s = fmaf(x[k], W[k * 32 + f], s);
    pre[which * 32 + f] = s;
}

// ---- prep2: fold adjacent linear maps into 5 32x32 mats + 5 vectors ----
// fold: [0)WA=uw2_0@uw1_1top [1024)WB=uw2_0@tw1_1 [2048)WC=tw2_0@uw1_0bot
//       [3072)WD=tw2_1@uw1_1bot [4096)WE=uw2_1@hw1_bot
//       [5120)vB [5152)vC [5184)vD [5216)addg2 [5248)dh2
__global__ __launch_bounds__(256) void k_prep2(
    const float* __restrict__ tw1, const float* __restrict__ tb1, const float* __restrict__ tw2,
    const float* __restrict__ tb2, const float* __restrict__ uw1, const float* __restrict__ ub1,
    const float* __restrict__ uw2, const float* __restrict__ ub2, const float* __restrict__ hw1,
    const float* __restrict__ pre, float* __restrict__ fold) {
    for (int e = threadIdx.x; e < 5 * 1024 + 5 * 32; e += 256) {
        if (e < 5120) {
            int m = e >> 10, r = e & 1023, i = r >> 5, j = r & 31;
            const float* A;
            const float* B;
            switch (m) {
                case 0: A = uw2;        B = uw1 + 2048; break;
                case 1: A = uw2;        B = tw1 + 1024; break;
                case 2: A = tw2;        B = uw1 + 1024; break;
                case 3: A = tw2 + 1024; B = uw1 + 3072; break;
                default: A = uw2 + 1024; B = hw1 + 1024; break;
            }
            float s = 0.f;
            for (int k = 0; k < 32; ++k) s = fmaf(A[i * 32 + k], B[k * 32 + j], s);
            fold[e] = s;
        } else {
            int r = e - 5120;
            int v = r >> 5, f = r & 31;
            const float* x;
            const float* B;
            float s;
            switch (v) {
                case 0: x = ub2;      B = tw1 + 1024; s = tb1[32 + f]; break;  // vB
                case 1: x = tb2;      B = uw1 + 1024; s = 0.f;         break;  // vC
                case 2: x = tb2 + 32; B = uw1 + 3072; s = 0.f;         break;  // vD
                case 3: x = ub2;      B = uw1 + 2048; s = ub1[32 + f]; break;  // addg2
                default: x = ub2 + 32; B = hw1 + 1024; s = pre[160 + f]; break;  // dh2
            }
            for (int k = 0; k < 32; ++k) s = fmaf(x[k], B[k * 32 + f], s);
            fold[e] = s;
        }
    }
}

// ---- fused accum0: per-edge v=lrelu(a*c1+d1), block-local segment-sum -> M0 ----
__global__ __launch_bounds__(256) void k_accum0f(const EdgeRec* __restrict__ rec,
                                                 const int* __restrict__ offs,
                                                 const int* __restrict__ nstart,
                                                 const float* __restrict__ pre,
                                                 float* __restrict__ M0, int nE) {
    __shared__ float zs[256 * 33];  // [slot][f], pad 33 -> conflict-free column reads
    __shared__ int woff[260];
    __shared__ int sh2[2];
    int tid = threadIdx.x, b = blockIdx.x;
    int s0 = b * BLK, s1 = min(s0 + BLK, nE);
    if (tid == 0) {
        int nlo = nstart[b];
        sh2[0] = nlo;
        sh2[1] = nstart[b + 1] - nlo + 1;
    }
    __syncthreads();
    int nlo = sh2[0], nwin = sh2[1];
    for (int i = tid; i < nwin + 1; i += 256) woff[i] = offs[nlo + i];
    int s = s0 + tid;
    if (s < s1) {
        float a = rec[s].a;
#pragma unroll
        for (int f = 0; f < DD; ++f) zs[tid * 33 + f] = lrelu(fmaf(a, pre[f], pre[32 + f]));
    }
    __syncthreads();
    for (int t = tid; t < nwin * DD; t += 256) {
        int ln = t >> 5, f = t & 31;
        int lo = max(woff[ln], s0), hi = min(woff[ln + 1], s1);
        if (lo >= hi) continue;
        float sum = 0.f;
        for (int j = lo; j < hi; ++j) sum += zs[(j - s0) * 33 + f];
        int n = nlo + ln;
        bool interior = (woff[ln] >= s0) && (woff[ln + 1] <= s1);
        if (interior) M0[(size_t)n * DD + f] = sum;
        else atomicAdd(&M0[(size_t)n * DD + f], sum);
    }
}

// ---- gnode: g[n] = addv + deg*dv + M[n]@W (thread per (node,f); lane-varying f -> LDS) ----
__global__ __launch_bounds__(256) void k_gnode(const float* __restrict__ M,
                                               const float* __restrict__ W,
                                               const float* __restrict__ dv,
                                               const float* __restrict__ addv,
                                               const int* __restrict__ off, float* __restrict__ g) {
    __shared__ float LW[1088];
    lds_copy(LW, W, 1024);
    lds_copy(LW + 1024, dv, 32);
    lds_copy(LW + 1056, addv, 32);
    __syncthreads();
    int tid = blockIdx.x * 256 + threadIdx.x;
    int n = tid >> 5, f = tid & 31;
    if (n >= NN) return;
    float deg = (float)(off[n + 1] - off[n]);
    const float* srow = M + (size_t)n * DD;
    float acc = fmaf(deg, LW[1024 + f], LW[1056 + f]);
    for (int k = 0; k < 32; ++k) acc = fmaf(srow[k], LW[k * 32 + f], acc);
    g[(size_t)n * DD + f] = acc;
}

// ---- fused z1: z=lrelu(WB@m+vB), m=lrelu(a*cu+g1[src]); block segment-sum -> Z1 ----
__global__ __launch_bounds__(256) void k_z1f(const EdgeRec* __restrict__ rec,
                                             const int* __restrict__ offs,
                                             const int* __restrict__ nstart,
                                             const float* __restrict__ pre,
                                             const float* __restrict__ fold,
                                             const float* __restrict__ g1, float* __restrict__ Z1,
                                             int nE) {
    __shared__ float zs[256 * 33];
    __shared__ int woff[260];
    __shared__ int sh2[2];
    int tid = threadIdx.x, b = blockIdx.x;
    int s0 = b * BLK, s1 = min(s0 + BLK, nE);
    if (tid == 0) {
        int nlo = nstart[b];
        sh2[0] = nlo;
        sh2[1] = nstart[b + 1] - nlo + 1;
    }
    __syncthreads();
    int nlo = sh2[0], nwin = sh2[1];
    for (int i = tid; i < nwin + 1; i += 256) woff[i] = offs[nlo + i];
    int s = s0 + tid;
    if (s < s1) {
        EdgeRec r = rec[s];  // coalesced 8B; consecutive slots share src
        float m[DD];
        {
            float gg[DD];
            load_vec32(gg, g1 + (size_t)r.src * DD);  // L1-local
#pragma unroll
            for (int f = 0; f < DD; ++f) m[f] = lrelu(fmaf(r.a, pre[64 + f], gg[f]));
        }
        float z[DD];
#pragma unroll
        for (int f = 0; f < DD; ++f) z[f] = fold[5120 + f];  // vB (scalar)
        mv_s(z, fold + 1024, m);                             // WB (scalar weights)
#pragma unroll
        for (int f = 0; f < DD; ++f) zs[tid * 33 + f] = lrelu(z[f]);
    }
    __syncthreads();
    for (int t = tid; t < nwin * DD; t += 256) {
        int ln = t >> 5, f = t & 31;
        int lo = max(woff[ln], s0), hi = min(woff[ln + 1], s1);
        if (lo >= hi) continue;
        float sum = 0.f;
        for (int j = lo; j < hi; ++j) sum += zs[(j - s0) * 33 + f];
        int n = nlo + ln;
        bool interior = (woff[ln] >= s0) && (woff[ln + 1] <= s1);
        if (interior) Z1[(size_t)n * DD + f] = sum;
        else atomicAdd(&Z1[(size_t)n * DD + f], sum);
    }
}

// ---- head (3 matvecs, scalar weights) + fused per-node denom ----
__global__ __launch_bounds__(256) void k_head3f(
    const EdgeRec* __restrict__ rec, const int* __restrict__ offs, const int* __restrict__ nstart,
    const float* __restrict__ pre, const float* __restrict__ fold, const float* __restrict__ hw2,
    const float* __restrict__ hb2, const float* __restrict__ hw3, const float* __restrict__ hb3,
    const float* __restrict__ g1, const float* __restrict__ g2, float* __restrict__ ev,
    float* __restrict__ denom, int nE) {
    __shared__ float evs[256];
    __shared__ int woff[260];
    __shared__ int sh2[2];
    int tid = threadIdx.x, b = blockIdx.x;
    int s0 = b * BLK, s1 = min(s0 + BLK, nE);
    if (tid == 0) {
        int nlo = nstart[b];
        sh2[0] = nlo;
        sh2[1] = nstart[b + 1] - nlo + 1;
    }
    __syncthreads();
    int nlo = sh2[0], nwin = sh2[1];
    for (int i = tid; i < nwin + 1; i += 256) woff[i] = offs[nlo + i];
    int s = s0 + tid;
    float exv = 0.f;
    if (s < s1) {
        EdgeRec r = rec[s];
        float m1[DD];
        {
            float gg[DD];
            load_vec32(gg, g1 + (size_t)r.src * DD);
#pragma unroll
            for (int f = 0; f < DD; ++f) m1[f] = lrelu(fmaf(r.a, pre[64 + f], gg[f]));
        }
        float z[DD];
        load_vec32(z, g2 + (size_t)r.src * DD);
        mv_s(z, fold, m1);  // WA
#pragma unroll
        for (int f = 0; f < DD; ++f) z[f] = lrelu(z[f]);  // m2
        float v[DD];
#pragma unroll
        for (int f = 0; f < DD; ++f) v[f] = fmaf(r.a, pre[128 + f], fold[5248 + f]);
        mv_s(v, fold + 4096, z);  // WE
#pragma unroll
        for (int f = 0; f < DD; ++f) v[f] = lrelu(v[f]);
        float w2[DD];
#pragma unroll
        for (int f = 0; f < DD; ++f) w2[f] = hb2[f];
        mv_s(w2, hw2, v);
        float val = hb3[0];
#pragma unroll
        for (int f = 0; f < DD; ++f) val = fmaf(lrelu(w2[f]), hw3[f], val);
        exv = __expf(val);  // max-shift dropped: logits O(1), math identical
        ev[s] = exv;
    }
    evs[tid] = exv;
    __syncthreads();
    for (int t = tid; t < nwin; t += 256) {
        int lo = max(woff[t], s0), hi = min(woff[t + 1], s1);
        if (lo >= hi) continue;
        float sum = 0.f;
        for (int j = lo; j < hi; ++j) sum += evs[j - s0];
        int n = nlo + t;
        bool interior = (woff[t] >= s0) && (woff[t + 1] <= s1);
        if (interior) denom[n] = sum;
        else atomicAdd(&denom[n], sum);
    }
}

// ---- final: out[e] = ev[inv[e]] / denom[ei[e]] (coalesced write, random gather) ----
__global__ __launch_bounds__(256) void k_final(const int* __restrict__ inv,
                                               const int* __restrict__ ei,
                                               const float* __restrict__ ev,
                                               const float* __restrict__ denom,
                                               float* __restrict__ out, int nE) {
    int e = blockIdx.x * 256 + threadIdx.x;
    if (e >= nE) return;
    out[e] = ev[inv[e]] / denom[ei[e]];
}

extern "C" void kernel_launch(void* const* d_in, const int* in_sizes, int n_in, void* d_out,
                              int out_size, void* d_ws, size_t ws_size, hipStream_t stream) {
    const float* ea = (const float*)d_in[0];
    const int* ei = (const int*)d_in[1];
    const float* w_in = (const float*)d_in[2];
    const float* b_in = (const float*)d_in[3];
    const float* tw1 = (const float*)d_in[4];
    const float* tb1 = (const float*)d_in[5];
    const float* tw2 = (const float*)d_in[6];
    const float* tb2 = (const float*)d_in[7];
    const float* uw1 = (const float*)d_in[8];
    const float* ub1 = (const float*)d_in[9];
    const float* uw2 = (const float*)d_in[10];
    const float* ub2 = (const float*)d_in[11];
    const float* hw1 = (const float*)d_in[12];
    const float* hb1 = (const float*)d_in[13];
    const float* hw2 = (const float*)d_in[14];
    const float* hb2 = (const float*)d_in[15];
    const float* hw3 = (const float*)d_in[16];
    const float* hb3 = (const float*)d_in[17];

    const int nE = in_sizes[0];
    const int gridB = (nE + BLK - 1) / BLK;

    char* w = (char*)d_ws;
    size_t pos = 0;
    auto alloc = [&](size_t bytes) -> void* {
        void* p = w + pos;
        pos = (pos + bytes + 255) & ~(size_t)255;
        return p;
    };
    int* cnt = (int*)alloc((size_t)NN * 4);
    int* offs = (int*)alloc((size_t)(NN + 1) * 4);
    int* nstart = (int*)alloc((size_t)(gridB + 1) * 4);
    EdgeRec* rec = (EdgeRec*)alloc((size_t)nE * sizeof(EdgeRec));
    int* inv = (int*)alloc((size_t)nE * 4);
    float* M0 = (float*)alloc((size_t)NN * DD * 4);  // M0|Z1|denom contiguous -> one memset
    float* Z1 = (float*)alloc((size_t)NN * DD * 4);
    float* denom = (float*)alloc((size_t)NN * 4);
    float* g1 = (float*)alloc((size_t)NN * DD * 4);
    float* g2 = (float*)alloc((size_t)NN * DD * 4);
    float* ev = (float*)alloc((size_t)nE * 4);
    float* pre = (float*)alloc(6 * 32 * 4);
    float* fold = (float*)alloc((5 * 1024 + 5 * 32) * 4);

    hipMemsetAsync(cnt, 0, (size_t)NN * 4, stream);
    hipMemsetAsync(M0, 0, ((size_t)2 * NN * DD + NN) * 4 + 512, stream);  // M0+Z1+denom (+pads)

    int gridE = (nE + 255) / 256;
    int gridNF = (NN * DD + 255) / 256;

    k_prep<<<1, 192, 0, stream>>>(w_in, b_in, tw1, tb1, uw1, ub1, hw1, hb1, pre);
    k_prep2<<<1, 256, 0, stream>>>(tw1, tb1, tw2, tb2, uw1, ub1, uw2, ub2, hw1, pre, fold);
    k_hist<<<gridE, 256, 0, stream>>>(ei, cnt, nE);
    k_scan<<<1, 1024, 0, stream>>>(cnt, offs, NN);
    k_fill<<<gridE, 256, 0, stream>>>(ei, ea, cnt, rec, inv, nE);
    k_bstart<<<(gridB + 256) / 256, 256, 0, stream>>>(offs, nstart, gridB, nE);

    // layer 0: fused per-edge compute + block-local segment-sum
    k_accum0f<<<gridB, 256, 0, stream>>>(rec, offs, nstart, pre, M0, nE);
    k_gnode<<<gridNF, 256, 0, stream>>>(M0, fold + 2048, fold + 5152, pre + 96, offs, g1);

    // layer 1: fused (1 matvec/edge) + block-local segment-sum
    k_z1f<<<gridB, 256, 0, stream>>>(rec, offs, nstart, pre, fold, g1, Z1, nE);
    k_gnode<<<gridNF, 256, 0, stream>>>(Z1, fold + 3072, fold + 5184, fold + 5216, offs, g2);

    // head (3 matvecs/edge, scalar weights) + fused denom
    k_head3f<<<gridB, 256, 0, stream>>>(rec, offs, nstart, pre, fold, hw2, hb2, hw3, hb3, g1, g2,
                                        ev, denom, nE);
    k_final<<<gridE, 256, 0, stream>>>(inv, ei, ev, denom, (float*)d_out, nE);
}

// Round 10
// 674.820 us; speedup vs baseline: 5.8452x; 1.2677x over previous
//
#include <hip/hip_runtime.h>

#define NN 50000
#define DD 32
#define BLK 256

typedef float f32x4 __attribute__((ext_vector_type(4)));
typedef _Float16 f16x8 __attribute__((ext_vector_type(8)));
typedef __fp16 fp16x2 __attribute__((ext_vector_type(2)));

struct __align__(8) EdgeRec {
    float a;
    int src;
};

union H8 {
    f16x8 h;
    unsigned u[4];
    uint4 u4;
};

__device__ __forceinline__ float lrelu(float x) { return fmaxf(x, 0.01f * x); }

__device__ __forceinline__ f32x4 lrelu4(f32x4 v) {
    f32x4 r;
    r[0] = fmaxf(v[0], 0.01f * v[0]);
    r[1] = fmaxf(v[1], 0.01f * v[1]);
    r[2] = fmaxf(v[2], 0.01f * v[2]);
    r[3] = fmaxf(v[3], 0.01f * v[3]);
    return r;
}

__device__ __forceinline__ unsigned pkrtz(float a, float b) {
    union {
        fp16x2 h;
        unsigned u;
    } x;
    x.h = __builtin_amdgcn_cvt_pkrtz(a, b);
    return x.u;
}

__device__ __forceinline__ f32x4 ld4(const float* __restrict__ p) {
    return *(const f32x4*)p;
}

__device__ __forceinline__ void lds_copy(float* dst, const float* __restrict__ src, int n) {
    for (int i = threadIdx.x; i < n; i += blockDim.x) dst[i] = src[i];
}

// ---------------- CSR build ----------------
__global__ __launch_bounds__(256) void k_hist(const int* __restrict__ ei, int* __restrict__ cnt,
                                              int nE) {
    int e = blockIdx.x * 256 + threadIdx.x;
    if (e < nE) atomicAdd(&cnt[ei[e]], 1);
}

__global__ __launch_bounds__(1024) void k_scan(int* __restrict__ cnt_cur, int* __restrict__ off,
                                               int nN) {
    __shared__ int part[1024];
    int t = threadIdx.x;
    const int CH = (nN + 1023) / 1024;
    int beg = t * CH, end = min(beg + CH, nN);
    int sum = 0;
    for (int i = beg; i < end; ++i) sum += cnt_cur[i];
    part[t] = sum;
    __syncthreads();
    for (int ofs = 1; ofs < 1024; ofs <<= 1) {
        int v = (t >= ofs) ? part[t - ofs] : 0;
        __syncthreads();
        part[t] += v;
        __syncthreads();
    }
    int run = (t == 0) ? 0 : part[t - 1];
    for (int i = beg; i < end; ++i) {
        int c = cnt_cur[i];
        off[i] = run;
        cnt_cur[i] = run;
        run += c;
    }
    if (t == 1023) off[nN] = part[1023];
}

__global__ __launch_bounds__(256) void k_fill(const int* __restrict__ ei,
                                              const float* __restrict__ ea, int* __restrict__ cur,
                                              EdgeRec* __restrict__ rec, int* __restrict__ inv,
                                              int nE) {
    int e = blockIdx.x * 256 + threadIdx.x;
    if (e >= nE) return;
    int src = ei[e];
    int pos = atomicAdd(&cur[src], 1);
    reinterpret_cast<int2*>(rec)[pos] = make_int2(__float_as_int(ea[e]), src);
    inv[e] = pos;
}

// nstart[b] = node containing slot min(b*BLK, nE-1)
__global__ __launch_bounds__(256) void k_bstart(const int* __restrict__ offs,
                                                int* __restrict__ nstart, int nB, int nE) {
    int b = blockIdx.x * 256 + threadIdx.x;
    if (b > nB) return;
    int s = min(b * BLK, nE - 1);
    int lo = 0, hi = NN - 1;
    while (lo < hi) {
        int mid = (lo + hi + 1) >> 1;
        if (offs[mid] <= s) lo = mid;
        else hi = mid - 1;
    }
    nstart[b] = lo;
}

// ---- prep: affine-in-a folds. pre = [c1,d1,cu,du,ch,dh] (6x32) ----
__global__ __launch_bounds__(192) void k_prep(const float* __restrict__ w_in,
                                              const float* __restrict__ b_in,
                                              const float* __restrict__ tw1,
                                              const float* __restrict__ tb1,
                                              const float* __restrict__ uw1,
                                              const float* __restrict__ ub1,
                                              const float* __restrict__ hw1,
                                              const float* __restrict__ hb1,
                                              float* __restrict__ pre) {
    int t = threadIdx.x;
    int which = t >> 5, f = t & 31;
    if (which >= 6) return;
    const float* W = (which < 2) ? tw1 : (which < 4) ? uw1 : hw1;
    const float* x = (which & 1) ? b_in : w_in;
    const float* badd = (which == 1) ? tb1 : (which == 3) ? ub1 : (which == 5) ? hb1 : nullptr;
    float s = badd ? badd[f] : 0.f;
    for (int k = 0; k < 32; ++k) s = fmaf(x[k], W[k * 32 + f], s);
    pre[which * 32 + f] = s;
}

// ---- prep2: fold adjacent linear maps + pack f16 MFMA A-fragments ----
// fold: [0)WA [1024)WB [2048)WC [3072)WD [4096)WE [5120)vB [5152)vC [5184)vD
//       [5216)addg2 [5248)dh2
// fragu (2048 u32): A-frags for mats {0=WB,1=WA,2=WE,3=hw2}, 2 tiles each,
// layout [(m*2+T)*64 + lane]*4 + dword. A[row][k] = Wlog[k][phi(row)] where
// phi = S-perm (8g+4t+r) for m<3 (zero-shuffle chaining) and identity for hw2.
__global__ __launch_bounds__(256) void k_prep2(
    const float* __restrict__ tw1, const float* __restrict__ tb1, const float* __restrict__ tw2,
    const float* __restrict__ tb2, const float* __restrict__ uw1, const float* __restrict__ ub1,
    const float* __restrict__ uw2, const float* __restrict__ ub2, const float* __restrict__ hw1,
    const float* __restrict__ hw2, const float* __restrict__ pre, float* __restrict__ fold,
    unsigned* __restrict__ fragu) {
    for (int e = threadIdx.x; e < 5 * 1024 + 5 * 32; e += 256) {
        if (e < 5120) {
            int m = e >> 10, r = e & 1023, i = r >> 5, j = r & 31;
            const float* A;
            const float* B;
            switch (m) {
                case 0: A = uw2;        B = uw1 + 2048; break;
                case 1: A = uw2;        B = tw1 + 1024; break;
                case 2: A = tw2;        B = uw1 + 1024; break;
                case 3: A = tw2 + 1024; B = uw1 + 3072; break;
                default: A = uw2 + 1024; B = hw1 + 1024; break;
            }
            float s = 0.f;
            for (int k = 0; k < 32; ++k) s = fmaf(A[i * 32 + k], B[k * 32 + j], s);
            fold[e] = s;
        } else {
            int r = e - 5120;
            int v = r >> 5, f = r & 31;
            const float* x;
            const float* B;
            float s;
            switch (v) {
                case 0: x = ub2;      B = tw1 + 1024; s = tb1[32 + f]; break;  // vB
                case 1: x = tb2;      B = uw1 + 1024; s = 0.f;         break;  // vC
                case 2: x = tb2 + 32; B = uw1 + 3072; s = 0.f;         break;  // vD
                case 3: x = ub2;      B = uw1 + 2048; s = ub1[32 + f]; break;  // addg2
                default: x = ub2 + 32; B = hw1 + 1024; s = pre[160 + f]; break;  // dh2
            }
            for (int k = 0; k < 32; ++k) s = fmaf(x[k], B[k * 32 + f], s);
            fold[e] = s;
        }
    }
    __syncthreads();
    for (int idx = threadIdx.x; idx < 2048; idx += 256) {
        int d = idx & 3;
        int l = (idx >> 2) & 63;
        int T = (idx >> 8) & 1;
        int m = idx >> 9;
        int row = 16 * T + (l & 15);
        int k0 = ((l >> 4) << 3) + 2 * d;
        const float* W = (m == 0) ? fold + 1024 : (m == 1) ? fold : (m == 2) ? fold + 4096 : hw2;
        int phi = (m == 3) ? row : (((row >> 2) & 3) * 8 + ((row >> 4) << 2) + (row & 3));
        union {
            _Float16 h[2];
            unsigned u;
        } P;
        P.h[0] = (_Float16)W[k0 * 32 + phi];
        P.h[1] = (_Float16)W[(k0 + 1) * 32 + phi];
        fragu[idx] = P.u;
    }
}

// ---- fused accum0: per-edge v=lrelu(a*c1+d1), block-local segment-sum -> M0 ----
__global__ __launch_bounds__(256) void k_accum0f(const EdgeRec* __restrict__ rec,
                                                 const int* __restrict__ offs,
                                                 const int* __restrict__ nstart,
                                                 const float* __restrict__ pre,
                                                 float* __restrict__ M0, int nE) {
    __shared__ float zs[256 * 33];
    __shared__ int woff[260];
    __shared__ int sh2[2];
    int tid = threadIdx.x, b = blockIdx.x;
    int s0 = b * BLK, s1 = min(s0 + BLK, nE);
    if (tid == 0) {
        int nlo = nstart[b];
        sh2[0] = nlo;
        sh2[1] = nstart[b + 1] - nlo + 1;
    }
    __syncthreads();
    int nlo = sh2[0], nwin = sh2[1];
    for (int i = tid; i < nwin + 1; i += 256) woff[i] = offs[nlo + i];
    int s = s0 + tid;
    if (s < s1) {
        float a = rec[s].a;
#pragma unroll
        for (int f = 0; f < DD; ++f) zs[tid * 33 + f] = lrelu(fmaf(a, pre[f], pre[32 + f]));
    }
    __syncthreads();
    for (int t = tid; t < nwin * DD; t += 256) {
        int ln = t >> 5, f = t & 31;
        int lo = max(woff[ln], s0), hi = min(woff[ln + 1], s1);
        if (lo >= hi) continue;
        float sum = 0.f;
        for (int j = lo; j < hi; ++j) sum += zs[(j - s0) * 33 + f];
        int n = nlo + ln;
        bool interior = (woff[ln] >= s0) && (woff[ln + 1] <= s1);
        if (interior) M0[(size_t)n * DD + f] = sum;
        else atomicAdd(&M0[(size_t)n * DD + f], sum);
    }
}

// ---- gnode: g[n] = addv + deg*dv + M[n]@W ----
__global__ __launch_bounds__(256) void k_gnode(const float* __restrict__ M,
                                               const float* __restrict__ W,
                                               const float* __restrict__ dv,
                                               const float* __restrict__ addv,
                                               const int* __restrict__ off, float* __restrict__ g) {
    __shared__ float LW[1088];
    lds_copy(LW, W, 1024);
    lds_copy(LW + 1024, dv, 32);
    lds_copy(LW + 1056, addv, 32);
    __syncthreads();
    int tid = blockIdx.x * 256 + threadIdx.x;
    int n = tid >> 5, f = tid & 31;
    if (n >= NN) return;
    float deg = (float)(off[n + 1] - off[n]);
    const float* srow = M + (size_t)n * DD;
    float acc = fmaf(deg, LW[1024 + f], LW[1056 + f]);
    for (int k = 0; k < 32; ++k) acc = fmaf(srow[k], LW[k * 32 + f], acc);
    g[(size_t)n * DD + f] = acc;
}

// ---- z1 via MFMA: z = lrelu(WB@m1 + vB), m1 = lrelu(a*cu + g1[src]) ----
// wave handles 16 edges/chunk, 4 chunks; C-frag written to LDS in logical order
__global__ __launch_bounds__(256) void k_z1m(const EdgeRec* __restrict__ rec,
                                             const int* __restrict__ offs,
                                             const int* __restrict__ nstart,
                                             const float* __restrict__ pre,
                                             const float* __restrict__ fold,
                                             const unsigned* __restrict__ fragu,
                                             const float* __restrict__ g1, float* __restrict__ Z1,
                                             int nE) {
    __shared__ __align__(16) float zs[256 * 36];  // stride 36: b128-aligned, ~2-way banks
    __shared__ int woff[260];
    __shared__ int sh2[2];
    int tid = threadIdx.x, b = blockIdx.x;
    int s0 = b * BLK, s1 = min(s0 + BLK, nE);
    if (tid == 0) {
        int nlo = nstart[b];
        sh2[0] = nlo;
        sh2[1] = nstart[b + 1] - nlo + 1;
    }
    __syncthreads();
    int nlo = sh2[0], nwin = sh2[1];
    for (int i = tid; i < nwin + 1; i += 256) woff[i] = offs[nlo + i];

    int l = tid & 63, g = l >> 4, e = l & 15, wv = tid >> 6;
    const uint4* fb = (const uint4*)fragu;
    H8 WB0, WB1;
    WB0.u4 = fb[0 + l];
    WB1.u4 = fb[64 + l];
    f32x4 cua = ld4(pre + 64 + 8 * g), cub = ld4(pre + 64 + 8 * g + 4);
    f32x4 vBa = ld4(fold + 5120 + 8 * g), vBb = ld4(fold + 5120 + 8 * g + 4);

    for (int c = 0; c < 4; ++c) {
        int ls = wv * 64 + c * 16 + e;  // local slot in block
        int slot = s0 + ls;
        int sc = min(slot, nE - 1);
        EdgeRec r = rec[sc];
        float a = r.a;
        const float* g1p = g1 + (size_t)r.src * DD + 8 * g;
        f32x4 ma = lrelu4(a * cua + ld4(g1p));
        f32x4 mb = lrelu4(a * cub + ld4(g1p + 4));
        H8 B;
        B.u[0] = pkrtz(ma[0], ma[1]);
        B.u[1] = pkrtz(ma[2], ma[3]);
        B.u[2] = pkrtz(mb[0], mb[1]);
        B.u[3] = pkrtz(mb[2], mb[3]);
        f32x4 z0 = __builtin_amdgcn_mfma_f32_16x16x32_f16(WB0.h, B.h, vBa, 0, 0, 0);
        f32x4 z1 = __builtin_amdgcn_mfma_f32_16x16x32_f16(WB1.h, B.h, vBb, 0, 0, 0);
        z0 = lrelu4(z0);
        z1 = lrelu4(z1);
        *(f32x4*)&zs[ls * 36 + 8 * g] = z0;      // features 8g..8g+3 (logical)
        *(f32x4*)&zs[ls * 36 + 8 * g + 4] = z1;  // features 8g+4..8g+7
    }
    __syncthreads();
    for (int t = tid; t < nwin * DD; t += 256) {
        int ln = t >> 5, f = t & 31;
        int lo = max(woff[ln], s0), hi = min(woff[ln + 1], s1);
        if (lo >= hi) continue;
        float sum = 0.f;
        for (int j = lo; j < hi; ++j) sum += zs[(j - s0) * 36 + f];
        int n = nlo + ln;
        bool interior = (woff[ln] >= s0) && (woff[ln + 1] <= s1);
        if (interior) Z1[(size_t)n * DD + f] = sum;
        else atomicAdd(&Z1[(size_t)n * DD + f], sum);
    }
}

// ---- head via MFMA (3 chained matvecs, zero-shuffle S-permuted weights) ----
__global__ __launch_bounds__(256) void k_head3m(
    const EdgeRec* __restrict__ rec, const int* __restrict__ offs, const int* __restrict__ nstart,
    const float* __restrict__ pre, const float* __restrict__ fold,
    const unsigned* __restrict__ fragu, const float* __restrict__ hb2,
    const float* __restrict__ hw3, const float* __restrict__ hb3, const float* __restrict__ g1,
    const float* __restrict__ g2, float* __restrict__ ev, float* __restrict__ denom, int nE) {
    __shared__ float evs[256];
    __shared__ int woff[260];
    __shared__ int sh2[2];
    int tid = threadIdx.x, b = blockIdx.x;
    int s0 = b * BLK, s1 = min(s0 + BLK, nE);
    if (tid == 0) {
        int nlo = nstart[b];
        sh2[0] = nlo;
        sh2[1] = nstart[b + 1] - nlo + 1;
    }
    evs[tid] = 0.f;
    __syncthreads();
    int nlo = sh2[0], nwin = sh2[1];
    for (int i = tid; i < nwin + 1; i += 256) woff[i] = offs[nlo + i];

    int l = tid & 63, g = l >> 4, e = l & 15, wv = tid >> 6;
    const uint4* fb = (const uint4*)fragu;
    H8 WA0, WA1, WE0, WE1, H0, H1;
    WA0.u4 = fb[128 + l];
    WA1.u4 = fb[192 + l];
    WE0.u4 = fb[256 + l];
    WE1.u4 = fb[320 + l];
    H0.u4 = fb[384 + l];
    H1.u4 = fb[448 + l];
    f32x4 cua = ld4(pre + 64 + 8 * g), cub = ld4(pre + 64 + 8 * g + 4);
    f32x4 cha = ld4(pre + 128 + 8 * g), chb = ld4(pre + 128 + 8 * g + 4);
    f32x4 dha = ld4(fold + 5248 + 8 * g), dhb = ld4(fold + 5248 + 8 * g + 4);
    f32x4 hb2a = ld4(hb2 + 4 * g), hb2b = ld4(hb2 + 16 + 4 * g);
    f32x4 h3a = ld4(hw3 + 4 * g), h3b = ld4(hw3 + 16 + 4 * g);
    float hb3s = hb3[0];

    for (int c = 0; c < 4; ++c) {
        int ls = wv * 64 + c * 16 + e;
        int slot = s0 + ls;
        int sc = min(slot, nE - 1);
        EdgeRec r = rec[sc];
        float a = r.a;
        const float* g1p = g1 + (size_t)r.src * DD + 8 * g;
        f32x4 ma = lrelu4(a * cua + ld4(g1p));
        f32x4 mb = lrelu4(a * cub + ld4(g1p + 4));
        H8 B;
        B.u[0] = pkrtz(ma[0], ma[1]);
        B.u[1] = pkrtz(ma[2], ma[3]);
        B.u[2] = pkrtz(mb[0], mb[1]);
        B.u[3] = pkrtz(mb[2], mb[3]);
        const float* g2p = g2 + (size_t)r.src * DD + 8 * g;
        f32x4 z0 = ld4(g2p), z1 = ld4(g2p + 4);  // C_in = g2 (incl. bias)
        z0 = __builtin_amdgcn_mfma_f32_16x16x32_f16(WA0.h, B.h, z0, 0, 0, 0);
        z1 = __builtin_amdgcn_mfma_f32_16x16x32_f16(WA1.h, B.h, z1, 0, 0, 0);
        z0 = lrelu4(z0);
        z1 = lrelu4(z1);
        B.u[0] = pkrtz(z0[0], z0[1]);
        B.u[1] = pkrtz(z0[2], z0[3]);
        B.u[2] = pkrtz(z1[0], z1[1]);
        B.u[3] = pkrtz(z1[2], z1[3]);
        f32x4 v0 = a * cha + dha, v1 = a * chb + dhb;  // C_in = a*ch + dh2
        v0 = __builtin_amdgcn_mfma_f32_16x16x32_f16(WE0.h, B.h, v0, 0, 0, 0);
        v1 = __builtin_amdgcn_mfma_f32_16x16x32_f16(WE1.h, B.h, v1, 0, 0, 0);
        v0 = lrelu4(v0);
        v1 = lrelu4(v1);
        B.u[0] = pkrtz(v0[0], v0[1]);
        B.u[1] = pkrtz(v0[2], v0[3]);
        B.u[2] = pkrtz(v1[0], v1[1]);
        B.u[3] = pkrtz(v1[2], v1[3]);
        f32x4 w0 = hb2a, w1 = hb2b;  // hw2 unpermuted: phys row = logical
        w0 = __builtin_amdgcn_mfma_f32_16x16x32_f16(H0.h, B.h, w0, 0, 0, 0);
        w1 = __builtin_amdgcn_mfma_f32_16x16x32_f16(H1.h, B.h, w1, 0, 0, 0);
        w0 = lrelu4(w0);
        w1 = lrelu4(w1);
        f32x4 t = w0 * h3a + w1 * h3b;
        float val = t[0] + t[1] + t[2] + t[3];
        val += __shfl_xor(val, 16, 64);
        val += __shfl_xor(val, 32, 64);
        float exv = __expf(val + hb3s);  // max-shift dropped: logits O(1)
        if (g == 0 && slot < s1) {
            ev[slot] = exv;
            evs[ls] = exv;
        }
    }
    __syncthreads();
    for (int t = tid; t < nwin; t += 256) {
        int lo = max(woff[t], s0), hi = min(woff[t + 1], s1);
        if (lo >= hi) continue;
        float sum = 0.f;
        for (int j = lo; j < hi; ++j) sum += evs[j - s0];
        int n = nlo + t;
        bool interior = (woff[t] >= s0) && (woff[t + 1] <= s1);
        if (interior) denom[n] = sum;
        else atomicAdd(&denom[n], sum);
    }
}

// ---- final: out[e] = ev[inv[e]] / denom[ei[e]] ----
__global__ __launch_bounds__(256) void k_final(const int* __restrict__ inv,
                                               const int* __restrict__ ei,
                                               const float* __restrict__ ev,
                                               const float* __restrict__ denom,
                                               float* __restrict__ out, int nE) {
    int e = blockIdx.x * 256 + threadIdx.x;
    if (e >= nE) return;
    out[e] = ev[inv[e]] / denom[ei[e]];
}

extern "C" void kernel_launch(void* const* d_in, const int* in_sizes, int n_in, void* d_out,
                              int out_size, void* d_ws, size_t ws_size, hipStream_t stream) {
    const float* ea = (const float*)d_in[0];
    const int* ei = (const int*)d_in[1];
    const float* w_in = (const float*)d_in[2];
    const float* b_in = (const float*)d_in[3];
    const float* tw1 = (const float*)d_in[4];
    const float* tb1 = (const float*)d_in[5];
    const float* tw2 = (const float*)d_in[6];
    const float* tb2 = (const float*)d_in[7];
    const float* uw1 = (const float*)d_in[8];
    const float* ub1 = (const float*)d_in[9];
    const float* uw2 = (const float*)d_in[10];
    const float* ub2 = (const float*)d_in[11];
    const float* hw1 = (const float*)d_in[12];
    const float* hb1 = (const float*)d_in[13];
    const float* hw2 = (const float*)d_in[14];
    const float* hb2 = (const float*)d_in[15];
    const float* hw3 = (const float*)d_in[16];
    const float* hb3 = (const float*)d_in[17];

    const int nE = in_sizes[0];
    const int gridB = (nE + BLK - 1) / BLK;

    char* w = (char*)d_ws;
    size_t pos = 0;
    auto alloc = [&](size_t bytes) -> void* {
        void* p = w + pos;
        pos = (pos + bytes + 255) & ~(size_t)255;
        return p;
    };
    int* cnt = (int*)alloc((size_t)NN * 4);
    int* offs = (int*)alloc((size_t)(NN + 1) * 4);
    int* nstart = (int*)alloc((size_t)(gridB + 1) * 4);
    EdgeRec* rec = (EdgeRec*)alloc((size_t)nE * sizeof(EdgeRec));
    int* inv = (int*)alloc((size_t)nE * 4);
    float* M0 = (float*)alloc((size_t)NN * DD * 4);  // M0|Z1|denom contiguous -> one memset
    float* Z1 = (float*)alloc((size_t)NN * DD * 4);
    float* denom = (float*)alloc((size_t)NN * 4);
    float* g1 = (float*)alloc((size_t)NN * DD * 4);
    float* g2 = (float*)alloc((size_t)NN * DD * 4);
    float* ev = (float*)alloc((size_t)nE * 4);
    float* pre = (float*)alloc(6 * 32 * 4);
    float* fold = (float*)alloc((5 * 1024 + 5 * 32) * 4);
    unsigned* fragu = (unsigned*)alloc(2048 * 4);

    hipMemsetAsync(cnt, 0, (size_t)NN * 4, stream);
    hipMemsetAsync(M0, 0, ((size_t)2 * NN * DD + NN) * 4 + 512, stream);

    int gridE = (nE + 255) / 256;
    int gridNF = (NN * DD + 255) / 256;

    k_prep<<<1, 192, 0, stream>>>(w_in, b_in, tw1, tb1, uw1, ub1, hw1, hb1, pre);
    k_prep2<<<1, 256, 0, stream>>>(tw1, tb1, tw2, tb2, uw1, ub1, uw2, ub2, hw1, hw2, pre, fold,
                                   fragu);
    k_hist<<<gridE, 256, 0, stream>>>(ei, cnt, nE);
    k_scan<<<1, 1024, 0, stream>>>(cnt, offs, NN);
    k_fill<<<gridE, 256, 0, stream>>>(ei, ea, cnt, rec, inv, nE);
    k_bstart<<<(gridB + 256) / 256, 256, 0, stream>>>(offs, nstart, gridB, nE);

    // layer 0: fused per-edge compute + block-local segment-sum
    k_accum0f<<<gridB, 256, 0, stream>>>(rec, offs, nstart, pre, M0, nE);
    k_gnode<<<gridNF, 256, 0, stream>>>(M0, fold + 2048, fold + 5152, pre + 96, offs, g1);

    // layer 1: MFMA matvec + block-local segment-sum
    k_z1m<<<gridB, 256, 0, stream>>>(rec, offs, nstart, pre, fold, fragu, g1, Z1, nE);
    k_gnode<<<gridNF, 256, 0, stream>>>(Z1, fold + 3072, fold + 5184, fold + 5216, offs, g2);

    // head: 3 chained MFMA matvecs + fused denom
    k_head3m<<<gridB, 256, 0, stream>>>(rec, offs, nstart, pre, fold, fragu, hb2, hw3, hb3, g1, g2,
                                        ev, denom, nE);
    k_final<<<gridE, 256, 0, stream>>>(inv, ei, ev, denom, (float*)d_out, nE);
}